// Round 2
// baseline (2821.717 us; speedup 1.0000x reference)
//
#include <hip/hip_runtime.h>
#include <hip/hip_bf16.h>

#define T_STEPS 63
#define BATCHSZ 32
#define HID 512
#define VOCAB 32000

typedef __bf16 bf16x8 __attribute__((ext_vector_type(8)));
typedef float f32x4 __attribute__((ext_vector_type(4)));

__device__ __forceinline__ unsigned short f2bf(float f) {
    __hip_bfloat16 h = __float2bfloat16(f);
    return *reinterpret_cast<unsigned short*>(&h);
}
__device__ __forceinline__ float sigm(float x) { return 1.0f / (1.0f + __expf(-x)); }

// ---------------------------------------------------------------------------
// init: h0 = features @ init_h_w^T + b ; c0 likewise; broadcast to both layers
// grid 64 x 256  (one thread per (b, j), two dot products of length 512)
// ---------------------------------------------------------------------------
__global__ __launch_bounds__(256) void init_kernel(
    const float* __restrict__ feat, const float* __restrict__ ihw,
    const float* __restrict__ ihb, const float* __restrict__ icw,
    const float* __restrict__ icb, float* __restrict__ Hbuf0,
    float* __restrict__ Cst)
{
    int n = blockIdx.x * 256 + threadIdx.x;   // 0..16383
    int b = n >> 9, j = n & 511;
    const float* fr = feat + b * 512;
    const float* hr = ihw + (size_t)j * 512;
    const float* cr = icw + (size_t)j * 512;
    float sh = 0.f, sc = 0.f;
    for (int k = 0; k < 512; k += 4) {
        float4 fv = *reinterpret_cast<const float4*>(fr + k);
        float4 hv = *reinterpret_cast<const float4*>(hr + k);
        float4 cv = *reinterpret_cast<const float4*>(cr + k);
        sh += fv.x * hv.x + fv.y * hv.y + fv.z * hv.z + fv.w * hv.w;
        sc += fv.x * cv.x + fv.y * cv.y + fv.z * cv.z + fv.w * cv.w;
    }
    sh += ihb[j];
    sc += icb[j];
    int off = b * 512 + j;
    Hbuf0[off] = sh; Hbuf0[BATCHSZ * 512 + off] = sh;   // layer 0, layer 1
    Cst[off]   = sc; Cst[BATCHSZ * 512 + off]   = sc;
}

// ---------------------------------------------------------------------------
// one LSTM step for one layer.
// grid (64 jj-chunks, 4 batch-groups) x 256 threads.
// thread = (kq 0..7, gate 0..3, jj-local 0..7); accumulates 8 batch rows.
// ---------------------------------------------------------------------------
__global__ __launch_bounds__(256) void lstm_step(
    const float* __restrict__ Wf, const float* __restrict__ Wi,
    const float* __restrict__ Wc, const float* __restrict__ Wo,
    const float* __restrict__ bfp, const float* __restrict__ bip,
    const float* __restrict__ bcp, const float* __restrict__ bop,
    const float* __restrict__ emb, const int* __restrict__ caps,
    const float* __restrict__ hcur, float* __restrict__ hnew,
    float* __restrict__ cst, unsigned short* __restrict__ h1all,
    int l, int t)
{
    __shared__ float comb[8][1024];          // 8 batch rows x (x_t | h_l)
    __shared__ float red[4 * 8 * 8 * 8];     // [gate][jj][b][kq]
    const int tid = threadIdx.x;
    const int b0 = blockIdx.y * 8;

    // stage comb (fp32)
    for (int i = tid; i < 8 * 1024; i += 256) {
        int b = i >> 10, k = i & 1023;
        float v;
        if (k < 512) {
            if (l == 0) {
                int tok = caps[(b0 + b) * 64 + t];
                v = emb[(size_t)tok * 512 + k];
            } else {
                v = hnew[(b0 + b) * 512 + k];           // layer-0 h at this t
            }
        } else {
            v = hcur[l * BATCHSZ * 512 + (b0 + b) * 512 + (k - 512)];
        }
        comb[b][k] = v;
    }
    __syncthreads();

    const int kq = tid >> 5, rl = tid & 31, g = rl >> 3, jjl = rl & 7;
    const int jj = blockIdx.x * 8 + jjl;
    const float* Wg = (g == 0) ? Wf : (g == 1) ? Wi : (g == 2) ? Wc : Wo;
    const float* wrow = Wg + ((size_t)(l * 512 + jj)) * 1024 + kq * 128;

    float acc[8];
    #pragma unroll
    for (int b = 0; b < 8; ++b) acc[b] = 0.f;

    for (int kk = 0; kk < 128; kk += 8) {
        float4 wa = *reinterpret_cast<const float4*>(wrow + kk);
        float4 wb = *reinterpret_cast<const float4*>(wrow + kk + 4);
        const float* cb = &comb[0][kq * 128 + kk];
        #pragma unroll
        for (int b = 0; b < 8; ++b) {
            const float* c8 = cb + b * 1024;
            acc[b] += wa.x * c8[0] + wa.y * c8[1] + wa.z * c8[2] + wa.w * c8[3]
                    + wb.x * c8[4] + wb.y * c8[5] + wb.z * c8[6] + wb.w * c8[7];
        }
    }
    #pragma unroll
    for (int b = 0; b < 8; ++b)
        red[(((g * 8 + jjl) * 8 + b) << 3) + kq] = acc[b];
    __syncthreads();

    if (tid < 64) {
        int jl = tid & 7, b = tid >> 3;
        int jglob = blockIdx.x * 8 + jl;
        int bglob = b0 + b;
        float s[4];
        #pragma unroll
        for (int g2 = 0; g2 < 4; ++g2) {
            const float* r = &red[(((g2 * 8 + jl) * 8 + b) << 3)];
            s[g2] = ((r[0] + r[1]) + (r[2] + r[3])) + ((r[4] + r[5]) + (r[6] + r[7]));
        }
        s[0] += bfp[l * 512 + jglob];
        s[1] += bip[l * 512 + jglob];
        s[2] += bcp[l * 512 + jglob];
        s[3] += bop[l * 512 + jglob];
        float fg = sigm(s[0]), ig = sigm(s[1]), ct = tanhf(s[2]), og = sigm(s[3]);
        float* cp = cst + (size_t)l * BATCHSZ * 512 + bglob * 512 + jglob;
        float cn = fg * (*cp) + ig * ct;
        *cp = cn;
        float hn = og * tanhf(cn);
        hnew[l * BATCHSZ * 512 + bglob * 512 + jglob] = hn;
        if (l == 1)
            h1all[((size_t)t * BATCHSZ + bglob) * 512 + jglob] = f2bf(hn);
    }
}

// ---------------------------------------------------------------------------
// projection: C(2016 x 32000) = H(2016 x 512) @ out_w^T + out_b, fp32 out
// with row remap (t*32+b) -> (b*63+t). 128x128 tile, BK=64, 4 waves of 64x64.
// H is pre-converted bf16 (h1all); W converted fp32->bf16 during staging.
// grid (bm=16 fastest, bn=250) so W-tile sharers are dispatch-adjacent.
// ---------------------------------------------------------------------------
__global__ __launch_bounds__(256) void proj_gemm(
    const unsigned short* __restrict__ H, const float* __restrict__ W,
    const float* __restrict__ bias, float* __restrict__ out)
{
    __shared__ unsigned short sA[128 * 72];
    __shared__ unsigned short sB[128 * 72];
    const int tid = threadIdx.x;
    const int bm = blockIdx.x, bn = blockIdx.y;
    const int wave = tid >> 6, lane = tid & 63;
    const int wm = (wave >> 1) << 6, wn = (wave & 1) << 6;
    const int lr = lane & 15, quad = lane >> 4;

    f32x4 acc[4][4];
    #pragma unroll
    for (int i = 0; i < 4; ++i)
        #pragma unroll
        for (int j = 0; j < 4; ++j) acc[i][j] = (f32x4){0.f, 0.f, 0.f, 0.f};

    for (int k0 = 0; k0 < 512; k0 += 64) {
        __syncthreads();
        // A: 128x64 bf16 = 1024 uint4 chunks, 4 per thread
        #pragma unroll
        for (int it = 0; it < 4; ++it) {
            int c = tid + (it << 8);           // 0..1023
            int row = c >> 3, col = (c & 7) << 3;
            int gm = (bm << 7) + row;
            uint4 av = make_uint4(0u, 0u, 0u, 0u);
            if (gm < 2016)
                av = *reinterpret_cast<const uint4*>(&H[(size_t)gm * 512 + k0 + col]);
            *reinterpret_cast<uint4*>(&sA[row * 72 + col]) = av;
        }
        // B: 128x64 fp32 = 2048 float4 chunks, 8 per thread; convert to bf16
        #pragma unroll
        for (int it = 0; it < 8; ++it) {
            int c = tid + (it << 8);           // 0..2047
            int row = c >> 4, col = (c & 15) << 2;
            int gn = (bn << 7) + row;
            float4 bv = *reinterpret_cast<const float4*>(&W[(size_t)gn * 512 + k0 + col]);
            uint2 p;
            p.x = (unsigned int)f2bf(bv.x) | ((unsigned int)f2bf(bv.y) << 16);
            p.y = (unsigned int)f2bf(bv.z) | ((unsigned int)f2bf(bv.w) << 16);
            *reinterpret_cast<uint2*>(&sB[row * 72 + col]) = p;
        }
        __syncthreads();
        #pragma unroll
        for (int ks = 0; ks < 2; ++ks) {
            bf16x8 af[4], bg[4];
            #pragma unroll
            for (int i = 0; i < 4; ++i)
                af[i] = *reinterpret_cast<const bf16x8*>(
                    &sA[(wm + (i << 4) + lr) * 72 + (ks << 5) + (quad << 3)]);
            #pragma unroll
            for (int i = 0; i < 4; ++i)
                bg[i] = *reinterpret_cast<const bf16x8*>(
                    &sB[(wn + (i << 4) + lr) * 72 + (ks << 5) + (quad << 3)]);
            #pragma unroll
            for (int mi = 0; mi < 4; ++mi)
                #pragma unroll
                for (int ni = 0; ni < 4; ++ni)
                    acc[mi][ni] = __builtin_amdgcn_mfma_f32_16x16x32_bf16(
                        af[mi], bg[ni], acc[mi][ni], 0, 0, 0);
        }
    }

    #pragma unroll
    for (int ni = 0; ni < 4; ++ni) {
        int n = (bn << 7) + wn + (ni << 4) + lr;
        float bv = bias[n];
        #pragma unroll
        for (int mi = 0; mi < 4; ++mi) {
            #pragma unroll
            for (int r = 0; r < 4; ++r) {
                int m = (bm << 7) + wm + (mi << 4) + (quad << 2) + r;
                if (m < 2016) {
                    int b = m & 31, tt = m >> 5;
                    out[((size_t)(b * 63 + tt)) * VOCAB + n] = acc[mi][ni][r] + bv;
                }
            }
        }
    }
}

extern "C" void kernel_launch(void* const* d_in, const int* in_sizes, int n_in,
                              void* d_out, int out_size, void* d_ws, size_t ws_size,
                              hipStream_t stream) {
    const float* feat = (const float*)d_in[0];
    const int*   caps = (const int*)d_in[1];
    const float* emb  = (const float*)d_in[2];
    const float* Wf   = (const float*)d_in[3];
    const float* bfp  = (const float*)d_in[4];
    const float* Wi   = (const float*)d_in[5];
    const float* bip  = (const float*)d_in[6];
    const float* Wc   = (const float*)d_in[7];
    const float* bcp  = (const float*)d_in[8];
    const float* Wo   = (const float*)d_in[9];
    const float* bop  = (const float*)d_in[10];
    const float* Wout = (const float*)d_in[11];
    const float* bout = (const float*)d_in[12];
    const float* ihw  = (const float*)d_in[13];
    const float* ihb  = (const float*)d_in[14];
    const float* icw  = (const float*)d_in[15];
    const float* icb  = (const float*)d_in[16];

    char* ws = (char*)d_ws;
    float* Hbuf0 = (float*)ws;                         // 2*32*512 f32 = 128 KB
    float* Hbuf1 = (float*)(ws + 131072);              // 128 KB
    float* Cst   = (float*)(ws + 262144);              // 128 KB
    unsigned short* h1all = (unsigned short*)(ws + 393216);  // 2016*512 bf16 ~ 2 MB

    init_kernel<<<dim3(64), dim3(256), 0, stream>>>(feat, ihw, ihb, icw, icb, Hbuf0, Cst);

    for (int t = 0; t < T_STEPS; ++t) {
        float* hcur = (t & 1) ? Hbuf1 : Hbuf0;
        float* hnew = (t & 1) ? Hbuf0 : Hbuf1;
        lstm_step<<<dim3(64, 4), dim3(256), 0, stream>>>(
            Wf, Wi, Wc, Wo, bfp, bip, bcp, bop, emb, caps,
            hcur, hnew, Cst, h1all, 0, t);
        lstm_step<<<dim3(64, 4), dim3(256), 0, stream>>>(
            Wf, Wi, Wc, Wo, bfp, bip, bcp, bop, emb, caps,
            hcur, hnew, Cst, h1all, 1, t);
    }

    proj_gemm<<<dim3(16, 250), dim3(256), 0, stream>>>(h1all, Wout, bout,
                                                       (float*)d_out);
}